// Round 1
// baseline (148.977 us; speedup 1.0000x reference)
//
#include <hip/hip_runtime.h>

typedef __bf16 bf16x8 __attribute__((ext_vector_type(8)));
typedef float f32x4 __attribute__((ext_vector_type(4)));

#define DEV static __device__ __forceinline__

DEV unsigned short f2b(float f){
    unsigned int u = __float_as_uint(f);
    u += 0x7fffu + ((u >> 16) & 1u);
    return (unsigned short)(u >> 16);
}
DEV float b2f(unsigned short h){ return __uint_as_float(((unsigned int)h) << 16); }
DEV float gelu_f(float x){ return 0.5f * x * (1.0f + erff(x * 0.7071067811865476f)); }

// ---------------------------------------------------------------- constants
static constexpr int NROW = 8192;   // B*D*H*W = 2*16*16*16
static constexpr int C    = 256;
static constexpr int F    = 1024;

// ---------------------------------------------------------------- weight prep
// Transpose + bf16-convert all weight matrices so GEMM B-operand reads
// WT[n][k] contiguously in k (MFMA B-fragment layout).
__global__ __launch_bounds__(256)
void prep_kernel(const float* __restrict__ Wq, const float* __restrict__ Wk,
                 const float* __restrict__ Wv, const float* __restrict__ Wo,
                 const float* __restrict__ W1, const float* __restrict__ W2,
                 unsigned short* __restrict__ WQT, unsigned short* __restrict__ WKT,
                 unsigned short* __restrict__ WVT, unsigned short* __restrict__ WOT,
                 unsigned short* __restrict__ W1T, unsigned short* __restrict__ W2T)
{
    int idx = blockIdx.x * 256 + threadIdx.x;       // grid covers 786432
    if (idx < 262144) {                             // 4 square 256x256 mats
        int m = idx >> 16;
        int r = (idx >> 8) & 255;                   // k
        int c = idx & 255;                          // n
        const float* src = (m == 0) ? Wq : (m == 1) ? Wk : (m == 2) ? Wv : Wo;
        unsigned short* dst = (m == 0) ? WQT : (m == 1) ? WKT : (m == 2) ? WVT : WOT;
        dst[c * 256 + r] = f2b(src[r * 256 + c]);
    } else if (idx < 524288) {                      // W1: 256 x 1024
        int i = idx - 262144;
        int r = i >> 10, c = i & 1023;
        W1T[c * 256 + r] = f2b(W1[r * 1024 + c]);
    } else {                                        // W2: 1024 x 256
        int i = idx - 524288;
        int r = i >> 8, c = i & 255;
        W2T[c * 1024 + r] = f2b(W2[r * 256 + c]);
    }
}

// ---------------------------------------------------------------- layernorm
// One block per row, 256 threads (=C). Optionally also emits bf16 copy of input.
template<bool WRITE_XB>
__global__ __launch_bounds__(256)
void ln_kernel(const float* __restrict__ X, const float* __restrict__ g,
               const float* __restrict__ bta,
               unsigned short* __restrict__ OUT, unsigned short* __restrict__ XB)
{
    const int row = blockIdx.x;
    const int tid = threadIdx.x;
    const int wid = tid >> 6, lane = tid & 63;
    float v = X[(size_t)row * C + tid];

    float s = v;
    #pragma unroll
    for (int m = 32; m >= 1; m >>= 1) s += __shfl_xor(s, m);
    __shared__ float sm[8];
    if (lane == 0) sm[wid] = s;
    __syncthreads();
    float mean = (sm[0] + sm[1] + sm[2] + sm[3]) * (1.0f / 256.0f);

    float dv = v - mean;
    float s2 = dv * dv;
    #pragma unroll
    for (int m = 32; m >= 1; m >>= 1) s2 += __shfl_xor(s2, m);
    if (lane == 0) sm[4 + wid] = s2;
    __syncthreads();
    float var = (sm[4] + sm[5] + sm[6] + sm[7]) * (1.0f / 256.0f);

    float o = dv * (1.0f / sqrtf(var + 1e-5f)) * g[tid] + bta[tid];
    OUT[(size_t)row * C + tid] = f2b(o);
    if (WRITE_XB) XB[(size_t)row * C + tid] = f2b(v);
}

// ---------------------------------------------------------------- GEMM
// C[M][N] = A[M][K](bf16) @ W[K][N] + bias, with W given transposed WT[N][K] bf16.
// BM=64, BN=64, BK=32, 256 threads (4 waves), wave w owns cols w*16..w*16+15.
// MODE 0: out bf16 = acc+bias
// MODE 1: out bf16 = gelu(acc+bias)
// MODE 2: out f32  = acc+bias+res
template<int K, int N, int MODE>
__global__ __launch_bounds__(256)
void gemm_kernel(const unsigned short* __restrict__ A,
                 const unsigned short* __restrict__ BT,
                 const float* __restrict__ bias,
                 const float* __restrict__ res,
                 void* __restrict__ outp)
{
    constexpr int BM = 64, BN = 64, BK = 32;
    constexpr int NKT = K / BK;
    __shared__ unsigned short As[2][BM * BK];
    __shared__ unsigned short Bs[2][BN * BK];

    const int m0 = blockIdx.x * BM;
    const int n0 = blockIdx.y * BN;
    const int tid  = threadIdx.x;
    const int lane = tid & 63, wid = tid >> 6;
    const int srow = tid >> 2, schk = tid & 3;          // staging: row, 16B chunk

    const uint4* Ag = reinterpret_cast<const uint4*>(A + (size_t)(m0 + srow) * K) + schk;
    const uint4* Bg = reinterpret_cast<const uint4*>(BT + (size_t)(n0 + srow) * K) + schk;

    uint4 ra = Ag[0], rb = Bg[0];
    *reinterpret_cast<uint4*>(&As[0][srow * BK + schk * 8]) = ra;
    *reinterpret_cast<uint4*>(&Bs[0][srow * BK + schk * 8]) = rb;
    __syncthreads();

    f32x4 acc[4] = {};
    const int lr = lane & 15, lk = lane >> 4;

    for (int kt = 0; kt < NKT; ++kt) {
        if (kt + 1 < NKT) { ra = Ag[(kt + 1) * (BK / 8)]; rb = Bg[(kt + 1) * (BK / 8)]; }
        const unsigned short* as = As[kt & 1];
        const unsigned short* bs = Bs[kt & 1];
        bf16x8 bfr = *reinterpret_cast<const bf16x8*>(&bs[(wid * 16 + lr) * BK + lk * 8]);
        #pragma unroll
        for (int m = 0; m < 4; ++m) {
            bf16x8 afr = *reinterpret_cast<const bf16x8*>(&as[(m * 16 + lr) * BK + lk * 8]);
            acc[m] = __builtin_amdgcn_mfma_f32_16x16x32_bf16(afr, bfr, acc[m], 0, 0, 0);
        }
        if (kt + 1 < NKT) {
            int nb = (kt + 1) & 1;
            *reinterpret_cast<uint4*>(&As[nb][srow * BK + schk * 8]) = ra;
            *reinterpret_cast<uint4*>(&Bs[nb][srow * BK + schk * 8]) = rb;
            __syncthreads();
        }
    }

    const int col = n0 + wid * 16 + lr;
    const float bcol = bias[col];
    #pragma unroll
    for (int m = 0; m < 4; ++m) {
        #pragma unroll
        for (int r = 0; r < 4; ++r) {
            int row = m0 + m * 16 + lk * 4 + r;
            float v = acc[m][r] + bcol;
            if (MODE == 0) {
                ((unsigned short*)outp)[(size_t)row * N + col] = f2b(v);
            } else if (MODE == 1) {
                ((unsigned short*)outp)[(size_t)row * N + col] = f2b(gelu_f(v));
            } else {
                v += res[(size_t)row * N + col];
                ((float*)outp)[(size_t)row * N + col] = v;
            }
        }
    }
}

// ---------------------------------------------------------------- attention
// One block per voxel; thread = (head n = tid>>5, dim e = tid&31).
// 27 neighbors, center (kk=13) and out-of-bounds masked.
__global__ __launch_bounds__(256)
void attn_kernel(const unsigned short* __restrict__ Q,
                 const unsigned short* __restrict__ Kt,
                 const unsigned short* __restrict__ Vt,
                 unsigned short* __restrict__ AO)
{
    const int vox = blockIdx.x;
    const int b = vox >> 12, d = (vox >> 8) & 15, h = (vox >> 4) & 15, w = vox & 15;
    const int tid = threadIdx.x;
    const float scale = 0.17677669529663688f;       // 1/sqrt(32)

    float qv = b2f(Q[(size_t)vox * C + tid]) * scale;

    float sc[27];
    int   nrow[27];
    #pragma unroll
    for (int kk = 0; kk < 27; ++kk) {
        int di = kk / 9 - 1, hi = (kk / 3) % 3 - 1, wi = kk % 3 - 1;
        int nd = d + di, nh = h + hi, nw = w + wi;
        bool valid = (kk != 13) && ((unsigned)nd < 16u) && ((unsigned)nh < 16u) && ((unsigned)nw < 16u);
        if (valid) {
            int r = (b << 12) + (nd << 8) + (nh << 4) + nw;
            nrow[kk] = r;
            float kv = b2f(Kt[(size_t)r * C + tid]);
            float s = qv * kv;
            s += __shfl_xor(s, 16);
            s += __shfl_xor(s, 8);
            s += __shfl_xor(s, 4);
            s += __shfl_xor(s, 2);
            s += __shfl_xor(s, 1);
            sc[kk] = s;
        } else {
            sc[kk] = -INFINITY;
            nrow[kk] = -1;
        }
    }

    float mx = -INFINITY;
    #pragma unroll
    for (int kk = 0; kk < 27; ++kk) mx = fmaxf(mx, sc[kk]);
    float sum = 0.0f;
    #pragma unroll
    for (int kk = 0; kk < 27; ++kk) { float p = __expf(sc[kk] - mx); sc[kk] = p; sum += p; }
    float inv = 1.0f / sum;

    float acc = 0.0f;
    #pragma unroll
    for (int kk = 0; kk < 27; ++kk) {
        if (nrow[kk] >= 0) {
            float vv = b2f(Vt[(size_t)nrow[kk] * C + tid]);
            acc += sc[kk] * vv;
        }
    }
    AO[(size_t)vox * C + tid] = f2b(acc * inv);
}

// ---------------------------------------------------------------- launch
extern "C" void kernel_launch(void* const* d_in, const int* in_sizes, int n_in,
                              void* d_out, int out_size, void* d_ws, size_t ws_size,
                              hipStream_t stream)
{
    const float* x   = (const float*)d_in[0];
    const float* Wq  = (const float*)d_in[1];
    const float* bq  = (const float*)d_in[2];
    const float* Wk  = (const float*)d_in[3];
    const float* bk  = (const float*)d_in[4];
    const float* Wv  = (const float*)d_in[5];
    const float* bv  = (const float*)d_in[6];
    const float* Wo  = (const float*)d_in[7];
    const float* bo  = (const float*)d_in[8];
    const float* g1  = (const float*)d_in[9];
    const float* b1  = (const float*)d_in[10];
    const float* g2  = (const float*)d_in[11];
    const float* b2  = (const float*)d_in[12];
    const float* W1  = (const float*)d_in[13];
    const float* bf1 = (const float*)d_in[14];
    const float* W2  = (const float*)d_in[15];
    const float* bf2 = (const float*)d_in[16];

    char* ws = (char*)d_ws;
    size_t o = 0;
    unsigned short* WQT = (unsigned short*)(ws + o); o += (size_t)256 * 256 * 2;
    unsigned short* WKT = (unsigned short*)(ws + o); o += (size_t)256 * 256 * 2;
    unsigned short* WVT = (unsigned short*)(ws + o); o += (size_t)256 * 256 * 2;
    unsigned short* WOT = (unsigned short*)(ws + o); o += (size_t)256 * 256 * 2;
    unsigned short* W1T = (unsigned short*)(ws + o); o += (size_t)256 * 1024 * 2;
    unsigned short* W2T = (unsigned short*)(ws + o); o += (size_t)1024 * 256 * 2;
    unsigned short* tn  = (unsigned short*)(ws + o); o += (size_t)NROW * C * 2;
    unsigned short* xb  = (unsigned short*)(ws + o); o += (size_t)NROW * C * 2;
    unsigned short* Qb  = (unsigned short*)(ws + o); o += (size_t)NROW * C * 2;
    unsigned short* Kb  = (unsigned short*)(ws + o); o += (size_t)NROW * C * 2;
    unsigned short* Vb  = (unsigned short*)(ws + o); o += (size_t)NROW * C * 2;
    unsigned short* AOb = (unsigned short*)(ws + o); o += (size_t)NROW * C * 2;
    float*          Tf  = (float*)(ws + o);          o += (size_t)NROW * C * 4;
    unsigned short* tn2 = (unsigned short*)(ws + o); o += (size_t)NROW * C * 2;
    unsigned short* Hb  = (unsigned short*)(ws + o); o += (size_t)NROW * F * 2;

    prep_kernel<<<3072, 256, 0, stream>>>(Wq, Wk, Wv, Wo, W1, W2,
                                          WQT, WKT, WVT, WOT, W1T, W2T);

    ln_kernel<true><<<NROW, 256, 0, stream>>>(x, g1, b1, tn, xb);

    gemm_kernel<256, 256, 0><<<dim3(NROW / 64, 4), 256, 0, stream>>>(tn, WQT, bq, nullptr, Qb);
    gemm_kernel<256, 256, 0><<<dim3(NROW / 64, 4), 256, 0, stream>>>(xb, WKT, bk, nullptr, Kb);
    gemm_kernel<256, 256, 0><<<dim3(NROW / 64, 4), 256, 0, stream>>>(xb, WVT, bv, nullptr, Vb);

    attn_kernel<<<NROW, 256, 0, stream>>>(Qb, Kb, Vb, AOb);

    gemm_kernel<256, 256, 2><<<dim3(NROW / 64, 4), 256, 0, stream>>>(AOb, WOT, bo, x, Tf);

    ln_kernel<false><<<NROW, 256, 0, stream>>>(Tf, g2, b2, tn2, nullptr);

    gemm_kernel<256, 1024, 1><<<dim3(NROW / 64, 16), 256, 0, stream>>>(tn2, W1T, bf1, nullptr, Hb);

    gemm_kernel<1024, 256, 2><<<dim3(NROW / 64, 4), 256, 0, stream>>>(Hb, W2T, bf2, Tf, (float*)d_out);
}

// Round 2
// 108.703 us; speedup vs baseline: 1.3705x; 1.3705x over previous
//
#include <hip/hip_runtime.h>

typedef __bf16 bf16x8 __attribute__((ext_vector_type(8)));
typedef float f32x4 __attribute__((ext_vector_type(4)));

#define DEV static __device__ __forceinline__

DEV unsigned short f2b(float f){
    unsigned int u = __float_as_uint(f);
    u += 0x7fffu + ((u >> 16) & 1u);
    return (unsigned short)(u >> 16);
}
DEV float b2f(unsigned short h){ return __uint_as_float(((unsigned int)h) << 16); }
DEV float gelu_f(float x){ return 0.5f * x * (1.0f + erff(x * 0.7071067811865476f)); }

// ---------------------------------------------------------------- constants
static constexpr int NROW = 8192;   // B*D*H*W = 2*16*16*16
static constexpr int C    = 256;
static constexpr int F    = 1024;

// ---------------------------------------------------------------- weight prep
// Transpose + bf16-convert weights; also build concatenated [bk|bv] bias.
__global__ __launch_bounds__(256)
void prep_kernel(const float* __restrict__ Wq, const float* __restrict__ Wk,
                 const float* __restrict__ Wv, const float* __restrict__ Wo,
                 const float* __restrict__ W1, const float* __restrict__ W2,
                 const float* __restrict__ bk, const float* __restrict__ bv,
                 unsigned short* __restrict__ WQT, unsigned short* __restrict__ WKT,
                 unsigned short* __restrict__ WVT, unsigned short* __restrict__ WOT,
                 unsigned short* __restrict__ W1T, unsigned short* __restrict__ W2T,
                 float* __restrict__ bkv)
{
    int idx = blockIdx.x * 256 + threadIdx.x;       // grid covers 786944
    if (idx < 262144) {                             // 4 square 256x256 mats
        int m = idx >> 16;
        int r = (idx >> 8) & 255;                   // k
        int c = idx & 255;                          // n
        const float* src = (m == 0) ? Wq : (m == 1) ? Wk : (m == 2) ? Wv : Wo;
        unsigned short* dst = (m == 0) ? WQT : (m == 1) ? WKT : (m == 2) ? WVT : WOT;
        dst[c * 256 + r] = f2b(src[r * 256 + c]);
    } else if (idx < 524288) {                      // W1: 256 x 1024
        int i = idx - 262144;
        int r = i >> 10, c = i & 1023;
        W1T[c * 256 + r] = f2b(W1[r * 1024 + c]);
    } else if (idx < 786432) {                      // W2: 1024 x 256
        int i = idx - 524288;
        int r = i >> 8, c = i & 255;
        W2T[c * 1024 + r] = f2b(W2[r * 256 + c]);
    } else {                                        // [bk|bv] concat
        int i = idx - 786432;                       // < 512
        bkv[i] = (i < 256) ? bk[i] : bv[i - 256];
    }
}

// ---------------------------------------------------------------- layernorm
template<bool WRITE_XB>
__global__ __launch_bounds__(256)
void ln_kernel(const float* __restrict__ X, const float* __restrict__ g,
               const float* __restrict__ bta,
               unsigned short* __restrict__ OUT, unsigned short* __restrict__ XB)
{
    const int row = blockIdx.x;
    const int tid = threadIdx.x;
    const int wid = tid >> 6, lane = tid & 63;
    float v = X[(size_t)row * C + tid];

    float s = v;
    #pragma unroll
    for (int m = 32; m >= 1; m >>= 1) s += __shfl_xor(s, m);
    __shared__ float sm[8];
    if (lane == 0) sm[wid] = s;
    __syncthreads();
    float mean = (sm[0] + sm[1] + sm[2] + sm[3]) * (1.0f / 256.0f);

    float dv = v - mean;
    float s2 = dv * dv;
    #pragma unroll
    for (int m = 32; m >= 1; m >>= 1) s2 += __shfl_xor(s2, m);
    if (lane == 0) sm[4 + wid] = s2;
    __syncthreads();
    float var = (sm[4] + sm[5] + sm[6] + sm[7]) * (1.0f / 256.0f);

    float o = dv * (1.0f / sqrtf(var + 1e-5f)) * g[tid] + bta[tid];
    OUT[(size_t)row * C + tid] = f2b(o);
    if (WRITE_XB) XB[(size_t)row * C + tid] = f2b(v);
}

// ---------------------------------------------------------------- GEMM
// C[M][N] = A[M][K](bf16) @ W[K][N] + bias, W given transposed WT[N][K] bf16.
// BM=64, BN=64, BK=32, 256 threads (4 waves).
// MODE 0: out bf16; MODE 1: out bf16 = gelu; MODE 2: out f32 = acc+bias+res
template<int K, int N, int MODE>
__global__ __launch_bounds__(256)
void gemm_kernel(const unsigned short* __restrict__ A,
                 const unsigned short* __restrict__ BT,
                 const float* __restrict__ bias,
                 const float* __restrict__ res,
                 void* __restrict__ outp)
{
    constexpr int BM = 64, BN = 64, BK = 32;
    constexpr int NKT = K / BK;
    __shared__ unsigned short As[2][BM * BK];
    __shared__ unsigned short Bs[2][BN * BK];

    const int m0 = blockIdx.x * BM;
    const int n0 = blockIdx.y * BN;
    const int tid  = threadIdx.x;
    const int lane = tid & 63, wid = tid >> 6;
    const int srow = tid >> 2, schk = tid & 3;          // staging: row, 16B chunk

    const uint4* Ag = reinterpret_cast<const uint4*>(A + (size_t)(m0 + srow) * K) + schk;
    const uint4* Bg = reinterpret_cast<const uint4*>(BT + (size_t)(n0 + srow) * K) + schk;

    uint4 ra = Ag[0], rb = Bg[0];
    *reinterpret_cast<uint4*>(&As[0][srow * BK + schk * 8]) = ra;
    *reinterpret_cast<uint4*>(&Bs[0][srow * BK + schk * 8]) = rb;
    __syncthreads();

    f32x4 acc[4] = {};
    const int lr = lane & 15, lk = lane >> 4;

    for (int kt = 0; kt < NKT; ++kt) {
        if (kt + 1 < NKT) { ra = Ag[(kt + 1) * (BK / 8)]; rb = Bg[(kt + 1) * (BK / 8)]; }
        const unsigned short* as = As[kt & 1];
        const unsigned short* bs = Bs[kt & 1];
        bf16x8 bfr = *reinterpret_cast<const bf16x8*>(&bs[(wid * 16 + lr) * BK + lk * 8]);
        #pragma unroll
        for (int m = 0; m < 4; ++m) {
            bf16x8 afr = *reinterpret_cast<const bf16x8*>(&as[(m * 16 + lr) * BK + lk * 8]);
            acc[m] = __builtin_amdgcn_mfma_f32_16x16x32_bf16(afr, bfr, acc[m], 0, 0, 0);
        }
        if (kt + 1 < NKT) {
            int nb = (kt + 1) & 1;
            *reinterpret_cast<uint4*>(&As[nb][srow * BK + schk * 8]) = ra;
            *reinterpret_cast<uint4*>(&Bs[nb][srow * BK + schk * 8]) = rb;
            __syncthreads();
        }
    }

    const int col = n0 + wid * 16 + lr;
    const float bcol = bias[col];
    #pragma unroll
    for (int m = 0; m < 4; ++m) {
        #pragma unroll
        for (int r = 0; r < 4; ++r) {
            int row = m0 + m * 16 + lk * 4 + r;
            float v = acc[m][r] + bcol;
            if (MODE == 0) {
                ((unsigned short*)outp)[(size_t)row * N + col] = f2b(v);
            } else if (MODE == 1) {
                ((unsigned short*)outp)[(size_t)row * N + col] = f2b(gelu_f(v));
            } else {
                v += res[(size_t)row * N + col];
                ((float*)outp)[(size_t)row * N + col] = v;
            }
        }
    }
}

// ---------------------------------------------------------------- attention
// 4 voxels per 256-thread block; each wave owns one voxel (wave-uniform masks).
// Thread = 4 contiguous channels of one head: lane l -> head l>>3, chans (l&7)*4.
// KV layout: [NROW][512] bf16, K in cols 0..255, V in cols 256..511.
__global__ __launch_bounds__(256)
void attn_kernel(const unsigned short* __restrict__ Q,
                 const unsigned short* __restrict__ KV,
                 unsigned short* __restrict__ AO)
{
    const int vox = blockIdx.x * 4 + (threadIdx.x >> 6);
    const int l   = threadIdx.x & 63;
    const int b = vox >> 12, d = (vox >> 8) & 15, h = (vox >> 4) & 15, w = vox & 15;
    const int ch = (l >> 3) * 32 + (l & 7) * 4;     // head*32 + lane-in-head*4
    const float scale = 0.17677669529663688f;       // 1/sqrt(32)

    ushort4 q4 = *reinterpret_cast<const ushort4*>(&Q[(size_t)vox * C + ch]);
    const float q0 = b2f(q4.x) * scale, q1 = b2f(q4.y) * scale;
    const float q2 = b2f(q4.z) * scale, q3 = b2f(q4.w) * scale;

    float sc[27];
    int   nrow[27];
    #pragma unroll
    for (int kk = 0; kk < 27; ++kk) {
        const int di = kk / 9 - 1, hi = (kk / 3) % 3 - 1, wi = kk % 3 - 1;
        int nd = d + di, nh = h + hi, nw = w + wi;
        bool valid = (kk != 13) && ((unsigned)nd < 16u) && ((unsigned)nh < 16u) && ((unsigned)nw < 16u);
        if (valid) {
            int r = (b << 12) + (nd << 8) + (nh << 4) + nw;
            nrow[kk] = r;
            ushort4 k4 = *reinterpret_cast<const ushort4*>(&KV[(size_t)r * 512 + ch]);
            float s = q0 * b2f(k4.x) + q1 * b2f(k4.y) + q2 * b2f(k4.z) + q3 * b2f(k4.w);
            s += __shfl_xor(s, 4);
            s += __shfl_xor(s, 2);
            s += __shfl_xor(s, 1);
            sc[kk] = s;
        } else {
            sc[kk] = -INFINITY;
            nrow[kk] = -1;
        }
    }

    float mx = -INFINITY;
    #pragma unroll
    for (int kk = 0; kk < 27; ++kk) mx = fmaxf(mx, sc[kk]);
    float sum = 0.0f;
    #pragma unroll
    for (int kk = 0; kk < 27; ++kk) { float p = __expf(sc[kk] - mx); sc[kk] = p; sum += p; }
    const float inv = 1.0f / sum;

    float a0 = 0.f, a1 = 0.f, a2 = 0.f, a3 = 0.f;
    #pragma unroll
    for (int kk = 0; kk < 27; ++kk) {
        if (nrow[kk] >= 0) {
            ushort4 v4 = *reinterpret_cast<const ushort4*>(&KV[(size_t)nrow[kk] * 512 + 256 + ch]);
            const float p = sc[kk];
            a0 += p * b2f(v4.x); a1 += p * b2f(v4.y);
            a2 += p * b2f(v4.z); a3 += p * b2f(v4.w);
        }
    }
    ushort4 o4 = { f2b(a0 * inv), f2b(a1 * inv), f2b(a2 * inv), f2b(a3 * inv) };
    *reinterpret_cast<ushort4*>(&AO[(size_t)vox * C + ch]) = o4;
}

// ---------------------------------------------------------------- launch
extern "C" void kernel_launch(void* const* d_in, const int* in_sizes, int n_in,
                              void* d_out, int out_size, void* d_ws, size_t ws_size,
                              hipStream_t stream)
{
    const float* x   = (const float*)d_in[0];
    const float* Wq  = (const float*)d_in[1];
    const float* bq  = (const float*)d_in[2];
    const float* Wk  = (const float*)d_in[3];
    const float* bk  = (const float*)d_in[4];
    const float* Wv  = (const float*)d_in[5];
    const float* bv  = (const float*)d_in[6];
    const float* Wo  = (const float*)d_in[7];
    const float* bo  = (const float*)d_in[8];
    const float* g1  = (const float*)d_in[9];
    const float* b1  = (const float*)d_in[10];
    const float* g2  = (const float*)d_in[11];
    const float* b2  = (const float*)d_in[12];
    const float* W1  = (const float*)d_in[13];
    const float* bf1 = (const float*)d_in[14];
    const float* W2  = (const float*)d_in[15];
    const float* bf2 = (const float*)d_in[16];

    char* ws = (char*)d_ws;
    size_t o = 0;
    unsigned short* WQT = (unsigned short*)(ws + o); o += (size_t)256 * 256 * 2;
    unsigned short* WKT = (unsigned short*)(ws + o); o += (size_t)256 * 256 * 2;   // [WKT|WVT] = [512][256]
    unsigned short* WVT = (unsigned short*)(ws + o); o += (size_t)256 * 256 * 2;
    unsigned short* WOT = (unsigned short*)(ws + o); o += (size_t)256 * 256 * 2;
    unsigned short* W1T = (unsigned short*)(ws + o); o += (size_t)256 * 1024 * 2;
    unsigned short* W2T = (unsigned short*)(ws + o); o += (size_t)1024 * 256 * 2;
    float*          bkv = (float*)(ws + o);          o += (size_t)512 * 4;
    unsigned short* tn  = (unsigned short*)(ws + o); o += (size_t)NROW * C * 2;
    unsigned short* xb  = (unsigned short*)(ws + o); o += (size_t)NROW * C * 2;
    unsigned short* Qb  = (unsigned short*)(ws + o); o += (size_t)NROW * C * 2;
    unsigned short* KVb = (unsigned short*)(ws + o); o += (size_t)NROW * 512 * 2;
    unsigned short* AOb = (unsigned short*)(ws + o); o += (size_t)NROW * C * 2;
    float*          Tf  = (float*)(ws + o);          o += (size_t)NROW * C * 4;
    unsigned short* tn2 = (unsigned short*)(ws + o); o += (size_t)NROW * C * 2;
    unsigned short* Hb  = (unsigned short*)(ws + o); o += (size_t)NROW * F * 2;

    prep_kernel<<<3074, 256, 0, stream>>>(Wq, Wk, Wv, Wo, W1, W2, bk, bv,
                                          WQT, WKT, WVT, WOT, W1T, W2T, bkv);

    ln_kernel<true><<<NROW, 256, 0, stream>>>(x, g1, b1, tn, xb);

    gemm_kernel<256, 256, 0><<<dim3(NROW / 64, 4), 256, 0, stream>>>(tn, WQT, bq, nullptr, Qb);
    gemm_kernel<256, 512, 0><<<dim3(NROW / 64, 8), 256, 0, stream>>>(xb, WKT, bkv, nullptr, KVb);

    attn_kernel<<<NROW / 4, 256, 0, stream>>>(Qb, KVb, AOb);

    gemm_kernel<256, 256, 2><<<dim3(NROW / 64, 4), 256, 0, stream>>>(AOb, WOT, bo, x, Tf);

    ln_kernel<false><<<NROW, 256, 0, stream>>>(Tf, g2, b2, tn2, nullptr);

    gemm_kernel<256, 1024, 1><<<dim3(NROW / 64, 16), 256, 0, stream>>>(tn2, W1T, bf1, nullptr, Hb);

    gemm_kernel<1024, 256, 2><<<dim3(NROW / 64, 4), 256, 0, stream>>>(Hb, W2T, bf2, Tf, (float*)d_out);
}